// Round 3
// baseline (42.469 us; speedup 1.0000x reference)
//
#include <hip/hip_runtime.h>

// RACNN crop+mask+resize fused kernel, 4-rows-per-block LDS staging version.
// images: (64, 3, 448, 448) f32, locs: (64, 3) f32 -> out: (64, 3, 224, 224) f32
//
// One block per (b, 4 output rows), all 3 channels. BLOCK=448 so the column
// window (W <= 448) is staged in a single coalesced iteration per (row,ch).
// Row-axis (axis 2) interp is block-uniform per output row; two source rows are
// pre-combined into LDS: comb[rr][c][j] = img[i0r][j]*mr0*(1-frr) + img[i1r][j]*mr1*frr.
// Each output pixel then needs 2 LDS reads + column mask/lerp:
//   out = comb[x0]*mq0*(1-frq) + comb[x1]*mq1*frq
// Identical to the reference modulo FP reassociation (absmax 0.016 << 0.092 thr).

#define B_N 64
#define C_N 3
#define S_N 448
#define O_N 224
#define BLOCK 448
#define RPB 4   // output rows per block

__device__ __forceinline__ float sigm(float x) {
    return 1.0f / (1.0f + __expf(-x));
}

__global__ __launch_bounds__(BLOCK) void racnn_crop_resize(
    const float* __restrict__ images,
    const float* __restrict__ locs,
    float* __restrict__ out) {
    __shared__ float comb[RPB][C_N][S_N];  // 21504 B

    const int r0 = blockIdx.x * RPB;  // first output row (axis 2)
    const int b = blockIdx.y;         // batch
    const int tid = threadIdx.x;

    const float fS = (float)S_N;

    // --- per-batch box params (match reference clip/floor/where order) ---
    float tx = locs[b * 3 + 0];
    float ty = locs[b * 3 + 1];
    float tl = locs[b * 3 + 2];
    tl = fminf(fmaxf(tl, fS / 3.0f), fS * (2.0f / 3.0f));
    tx = fminf(fmaxf(tx, tl), fS - tl);
    ty = fminf(fmaxf(ty, tl), fS - tl);

    float w_off = fmaxf(floorf(tx - tl), 0.0f);
    float w_end = (tx + tl < fS) ? floorf(tx + tl) : fS;
    float h_off = fmaxf(floorf(ty - tl), 0.0f);
    float h_end = (ty + tl < fS) ? floorf(ty + tl) : fS;

    // --- gathered column range (h_off/h_end are integral) ---
    const int col_lo = (int)h_off;                // >= 0
    const int col_hi = min((int)h_end, S_N - 1);  // i1q never exceeds this

    // --- per-row (axis-2) interp params, uniform across the block ---
    int i0r_[RPB], i1r_[RPB];
    float Ar[RPB], Br[RPB];
    const float inv_o1 = 1.0f / (float)(O_N - 1);
#pragma unroll
    for (int rr = 0; rr < RPB; ++rr) {
        float src_r = w_off + (float)(r0 + rr) * (w_end - w_off - 1.0f) * inv_o1;
        float f0r = fminf(fmaxf(floorf(src_r), 0.0f), fS - 1.0f);
        int i0r = (int)f0r;
        int i1r = min(i0r + 1, S_N - 1);
        float frr = src_r - f0r;
        float mr0 = sigm(10.0f * (f0r - w_off)) - sigm(10.0f * (f0r - w_end));
        float mr1 = sigm(10.0f * ((float)i1r - w_off)) - sigm(10.0f * ((float)i1r - w_end));
        i0r_[rr] = i0r;
        i1r_[rr] = i1r;
        Ar[rr] = mr0 * (1.0f - frr);
        Br[rr] = mr1 * frr;
    }

    // --- stage combined rows into LDS (coalesced, single iteration: W <= BLOCK) ---
    const size_t plane = (size_t)S_N * S_N;
    const float* base = images + (size_t)b * C_N * plane;
    const int j = col_lo + tid;
    if (j <= col_hi) {
#pragma unroll
        for (int rr = 0; rr < RPB; ++rr) {
            const float* p0 = base + (size_t)i0r_[rr] * S_N;
            const float* p1 = base + (size_t)i1r_[rr] * S_N;
            float a = Ar[rr], bb = Br[rr];
#pragma unroll
            for (int c = 0; c < C_N; ++c) {
                comb[rr][c][tid] = p0[c * plane + j] * a + p1[c * plane + j] * bb;
            }
        }
    }
    __syncthreads();

    // --- column (axis-3) interp + mask; 448 threads = 2 half-rows x 224 q ---
    const int q = tid % O_N;
    const int half = tid / O_N;  // 0 or 1

    float src_q = h_off + (float)q * (h_end - h_off - 1.0f) * inv_o1;
    float f0q = fminf(fmaxf(floorf(src_q), 0.0f), fS - 1.0f);
    int i0q = (int)f0q;
    int i1q = min(i0q + 1, S_N - 1);
    float frq = src_q - f0q;
    float mq0 = sigm(10.0f * (f0q - h_off)) - sigm(10.0f * (f0q - h_end));
    float mq1 = sigm(10.0f * ((float)i1q - h_off)) - sigm(10.0f * ((float)i1q - h_end));

    const int W = col_hi - col_lo + 1;
    int x0 = min(max(i0q - col_lo, 0), W - 1);
    int x1 = min(max(i1q - col_lo, 0), W - 1);
    float wa = mq0 * (1.0f - frq);
    float wb = mq1 * frq;

#pragma unroll
    for (int rr = 0; rr < 2; ++rr) {
        const int r_local = half + 2 * rr;  // half0: rows 0,2; half1: rows 1,3
        const int r = r0 + r_local;
#pragma unroll
        for (int c = 0; c < C_N; ++c) {
            float o = comb[r_local][c][x0] * wa + comb[r_local][c][x1] * wb;
            out[(((size_t)b * C_N + c) * O_N + r) * O_N + q] = o;
        }
    }
}

extern "C" void kernel_launch(void* const* d_in, const int* in_sizes, int n_in,
                              void* d_out, int out_size, void* d_ws, size_t ws_size,
                              hipStream_t stream) {
    const float* images = (const float*)d_in[0];
    const float* locs   = (const float*)d_in[1];
    float* out = (float*)d_out;

    dim3 grid(O_N / RPB, B_N);  // (56, 64) = 3584 blocks
    racnn_crop_resize<<<grid, BLOCK, 0, stream>>>(images, locs, out);
}

// Round 4
// 33.144 us; speedup vs baseline: 1.2814x; 1.2814x over previous
//
#include <hip/hip_runtime.h>

// RACNN crop+mask+resize fused kernel — round-2 structure + float4 staging
// + XCD-chunked block swizzle.
// images: (64, 3, 448, 448) f32, locs: (64, 3) f32 -> out: (64, 3, 224, 224) f32
//
// One block per (b, output row r), all 3 channels. Row-axis (axis 2) interp
// params are block-uniform; the two source rows are pre-combined into LDS via
// float4 loads over the 4-aligned column window:
//   comb[c][j] = img[i0r][j]*mr0*(1-frr) + img[i1r][j]*mr1*frr
// Each output pixel then needs 2 LDS reads + column mask/lerp.
// Identical to the reference modulo FP reassociation (absmax 0.016 << 0.092).

#define B_N 64
#define C_N 3
#define S_N 448
#define O_N 224
#define BLOCK 256
#define NXCD 8
#define NV_PAD 113  // max float4 per channel window (112) + 1 pad

__device__ __forceinline__ float sigm(float x) {
    return 1.0f / (1.0f + __expf(-x));
}

__global__ __launch_bounds__(BLOCK) void racnn_crop_resize(
    const float* __restrict__ images,
    const float* __restrict__ locs,
    float* __restrict__ out) {
    __shared__ float4 comb4[C_N][NV_PAD];  // 5424 B

    // XCD-chunked swizzle: hw block k dispatches to XCD k%8 (round-robin).
    // logical = (bid%8)*1792 + bid/8  (bijective: 14336 = 8*1792) gives each
    // XCD a contiguous logical range = 8 whole batches, so the source-row
    // overlap between adjacent output rows is reused within one XCD's L2.
    const int bid = blockIdx.x;
    const int logical = (bid % NXCD) * (O_N * B_N / NXCD) + bid / NXCD;
    const int r = logical % O_N;
    const int b = logical / O_N;
    const int tid = threadIdx.x;

    const float fS = (float)S_N;

    // --- per-batch box params (match reference clip/floor/where order) ---
    float tx = locs[b * 3 + 0];
    float ty = locs[b * 3 + 1];
    float tl = locs[b * 3 + 2];
    tl = fminf(fmaxf(tl, fS / 3.0f), fS * (2.0f / 3.0f));
    tx = fminf(fmaxf(tx, tl), fS - tl);
    ty = fminf(fmaxf(ty, tl), fS - tl);

    float w_off = fmaxf(floorf(tx - tl), 0.0f);
    float w_end = (tx + tl < fS) ? floorf(tx + tl) : fS;
    float h_off = fmaxf(floorf(ty - tl), 0.0f);
    float h_end = (ty + tl < fS) ? floorf(ty + tl) : fS;

    const float inv_o1 = 1.0f / (float)(O_N - 1);

    // --- row (axis-2) interp params: uniform across the block ---
    float src_r = w_off + (float)r * (w_end - w_off - 1.0f) * inv_o1;
    float f0r = fminf(fmaxf(floorf(src_r), 0.0f), fS - 1.0f);
    int i0r = (int)f0r;
    int i1r = min(i0r + 1, S_N - 1);
    float frr = src_r - f0r;
    float mr0 = sigm(10.0f * (f0r - w_off)) - sigm(10.0f * (f0r - w_end));
    float mr1 = sigm(10.0f * ((float)i1r - w_off)) - sigm(10.0f * ((float)i1r - w_end));
    const float A  = mr0 * (1.0f - frr);
    const float Bw = mr1 * frr;

    // --- 4-aligned gathered column window (h_off/h_end are integral) ---
    const int col_lo = (int)h_off;                // >= 0
    const int col_hi = min((int)h_end, S_N - 1);  // i1q never exceeds this
    const int c4lo = col_lo >> 2;
    const int nv = (col_hi >> 2) - c4lo + 1;      // <= 112 float4 per channel

    // --- stage combined rows into LDS (coalesced float4) ---
    const float4* img4 = reinterpret_cast<const float4*>(images);
    const size_t plane4 = (size_t)(S_N * S_N / 4);
    const size_t row4 = S_N / 4;  // 112
    const size_t base4 = (size_t)b * C_N * plane4;
    const size_t off0 = (size_t)i0r * row4 + c4lo;
    const size_t off1 = (size_t)i1r * row4 + c4lo;

    const int total = C_N * nv;  // <= 336, so at most 2 iterations
    for (int v = tid; v < total; v += BLOCK) {
        int c = (v >= nv) + (v >= 2 * nv);
        int j4 = v - c * nv;
        const float4 a = img4[base4 + (size_t)c * plane4 + off0 + j4];
        const float4 bb = img4[base4 + (size_t)c * plane4 + off1 + j4];
        float4 o;
        o.x = a.x * A + bb.x * Bw;
        o.y = a.y * A + bb.y * Bw;
        o.z = a.z * A + bb.z * Bw;
        o.w = a.w * A + bb.w * Bw;
        comb4[c][j4] = o;
    }
    __syncthreads();

    // --- column (axis-3) interp + mask, one output pixel per thread ---
    if (tid < O_N) {
        const int q = tid;
        float src_q = h_off + (float)q * (h_end - h_off - 1.0f) * inv_o1;
        float f0q = fminf(fmaxf(floorf(src_q), 0.0f), fS - 1.0f);
        int i0q = (int)f0q;
        int i1q = min(i0q + 1, S_N - 1);
        float frq = src_q - f0q;
        float mq0 = sigm(10.0f * (f0q - h_off)) - sigm(10.0f * (f0q - h_end));
        float mq1 = sigm(10.0f * ((float)i1q - h_off)) - sigm(10.0f * ((float)i1q - h_end));

        const int wlim = nv * 4 - 1;
        const int base_col = c4lo << 2;
        int x0 = min(max(i0q - base_col, 0), wlim);
        int x1 = min(max(i1q - base_col, 0), wlim);
        float wa = mq0 * (1.0f - frq);
        float wb = mq1 * frq;

        const float* combf = reinterpret_cast<const float*>(comb4);
#pragma unroll
        for (int c = 0; c < C_N; ++c) {
            float o = combf[c * (NV_PAD * 4) + x0] * wa +
                      combf[c * (NV_PAD * 4) + x1] * wb;
            out[(((size_t)b * C_N + c) * O_N + r) * O_N + q] = o;
        }
    }
}

extern "C" void kernel_launch(void* const* d_in, const int* in_sizes, int n_in,
                              void* d_out, int out_size, void* d_ws, size_t ws_size,
                              hipStream_t stream) {
    const float* images = (const float*)d_in[0];
    const float* locs   = (const float*)d_in[1];
    float* out = (float*)d_out;

    racnn_crop_resize<<<O_N * B_N, BLOCK, 0, stream>>>(images, locs, out);
}

// Round 5
// 32.626 us; speedup vs baseline: 1.3017x; 1.0159x over previous
//
#include <hip/hip_runtime.h>

// RACNN crop+mask+resize fused kernel — 2 rows/block, params hoisted above
// the staging barrier, float4 staging, XCD-chunked block swizzle.
// images: (64, 3, 448, 448) f32, locs: (64, 3) f32 -> out: (64, 3, 224, 224) f32
//
// One block per (b, 2 output rows), all 3 channels, BLOCK=256 (8 blocks/CU).
// Row-axis (axis 2) interp params are block-uniform; source rows pre-combined
// into LDS via float4 loads over the 4-aligned column window:
//   comb[rr][c][j] = img[i0r][j]*mr0*(1-frr) + img[i1r][j]*mr1*frr
// Column (axis 3) params are computed BEFORE the staging loop so the expf/VALU
// work overlaps the global-load latency. Output pixel = 2 LDS reads + lerp.
// Identical to the reference modulo FP reassociation (absmax 0.016 << 0.092).

#define B_N 64
#define C_N 3
#define S_N 448
#define O_N 224
#define BLOCK 256
#define RPB 2
#define NXCD 8
#define NV_PAD 113  // max float4 per channel window (112) + 1 pad

__device__ __forceinline__ float sigm(float x) {
    return 1.0f / (1.0f + __expf(-x));
}

__global__ __launch_bounds__(BLOCK) void racnn_crop_resize(
    const float* __restrict__ images,
    const float* __restrict__ locs,
    float* __restrict__ out) {
    __shared__ float4 comb4[RPB][C_N][NV_PAD];  // 10848 B

    // XCD-chunked swizzle: hw block k goes to XCD k%8; logical ids chunked so
    // each XCD gets 8 contiguous batches (7168 = 8*896, bijective).
    const int bid = blockIdx.x;
    const int nwg = (O_N / RPB) * B_N;  // 7168
    const int logical = (bid % NXCD) * (nwg / NXCD) + bid / NXCD;
    const int r0 = (logical % (O_N / RPB)) * RPB;
    const int b = logical / (O_N / RPB);
    const int tid = threadIdx.x;

    const float fS = (float)S_N;

    // --- per-batch box params (match reference clip/floor/where order) ---
    float tx = locs[b * 3 + 0];
    float ty = locs[b * 3 + 1];
    float tl = locs[b * 3 + 2];
    tl = fminf(fmaxf(tl, fS / 3.0f), fS * (2.0f / 3.0f));
    tx = fminf(fmaxf(tx, tl), fS - tl);
    ty = fminf(fmaxf(ty, tl), fS - tl);

    float w_off = fmaxf(floorf(tx - tl), 0.0f);
    float w_end = (tx + tl < fS) ? floorf(tx + tl) : fS;
    float h_off = fmaxf(floorf(ty - tl), 0.0f);
    float h_end = (ty + tl < fS) ? floorf(ty + tl) : fS;

    const float inv_o1 = 1.0f / (float)(O_N - 1);

    // --- 4-aligned gathered column window (h_off/h_end are integral) ---
    const int col_lo = (int)h_off;
    const int col_hi = min((int)h_end, S_N - 1);
    const int c4lo = col_lo >> 2;
    const int nv = (col_hi >> 2) - c4lo + 1;  // <= 112 float4 per channel

    // --- column (axis-3) params: computed NOW so expf overlaps load latency ---
    int x0 = 0, x1 = 0;
    float wa = 0.0f, wb = 0.0f;
    {
        const int q = tid;  // valid for tid < O_N; harmless garbage otherwise
        float src_q = h_off + (float)q * (h_end - h_off - 1.0f) * inv_o1;
        float f0q = fminf(fmaxf(floorf(src_q), 0.0f), fS - 1.0f);
        int i0q = (int)f0q;
        int i1q = min(i0q + 1, S_N - 1);
        float frq = src_q - f0q;
        float mq0 = sigm(10.0f * (f0q - h_off)) - sigm(10.0f * (f0q - h_end));
        float mq1 = sigm(10.0f * ((float)i1q - h_off)) - sigm(10.0f * ((float)i1q - h_end));
        const int wlim = nv * 4 - 1;
        const int base_col = c4lo << 2;
        x0 = min(max(i0q - base_col, 0), wlim);
        x1 = min(max(i1q - base_col, 0), wlim);
        wa = mq0 * (1.0f - frq);
        wb = mq1 * frq;
    }

    // --- row (axis-2) interp params per local row (block-uniform) ---
    size_t off0_[RPB], off1_[RPB];
    float Ar[RPB], Br[RPB];
    const size_t plane4 = (size_t)(S_N * S_N / 4);
    const size_t row4 = S_N / 4;  // 112
#pragma unroll
    for (int rr = 0; rr < RPB; ++rr) {
        float src_r = w_off + (float)(r0 + rr) * (w_end - w_off - 1.0f) * inv_o1;
        float f0r = fminf(fmaxf(floorf(src_r), 0.0f), fS - 1.0f);
        int i0r = (int)f0r;
        int i1r = min(i0r + 1, S_N - 1);
        float frr = src_r - f0r;
        float mr0 = sigm(10.0f * (f0r - w_off)) - sigm(10.0f * (f0r - w_end));
        float mr1 = sigm(10.0f * ((float)i1r - w_off)) - sigm(10.0f * ((float)i1r - w_end));
        Ar[rr] = mr0 * (1.0f - frr);
        Br[rr] = mr1 * frr;
        off0_[rr] = (size_t)i0r * row4 + c4lo;
        off1_[rr] = (size_t)i1r * row4 + c4lo;
    }

    // --- stage combined rows into LDS (coalesced float4) ---
    const float4* img4 = reinterpret_cast<const float4*>(images);
    const size_t base4 = (size_t)b * C_N * plane4;

    const int total = RPB * C_N * nv;  // <= 672 -> at most 3 iterations
    for (int v = tid; v < total; v += BLOCK) {
        int cc = v / nv;          // 0..5
        int j4 = v - cc * nv;
        int rr = cc >= C_N;       // RPB=2
        int c = cc - rr * C_N;
        const size_t cbase = base4 + (size_t)c * plane4;
        const float4 a = img4[cbase + off0_[rr] + j4];
        const float4 bb = img4[cbase + off1_[rr] + j4];
        float4 o;
        o.x = a.x * Ar[rr] + bb.x * Br[rr];
        o.y = a.y * Ar[rr] + bb.y * Br[rr];
        o.z = a.z * Ar[rr] + bb.z * Br[rr];
        o.w = a.w * Ar[rr] + bb.w * Br[rr];
        comb4[rr][c][j4] = o;
    }
    __syncthreads();

    // --- column lerp + store: one q per thread, 2 rows x 3 channels ---
    if (tid < O_N) {
        const int q = tid;
        const float* combf = reinterpret_cast<const float*>(comb4);
#pragma unroll
        for (int rr = 0; rr < RPB; ++rr) {
#pragma unroll
            for (int c = 0; c < C_N; ++c) {
                const float* row = combf + ((size_t)rr * C_N + c) * (NV_PAD * 4);
                float o = row[x0] * wa + row[x1] * wb;
                out[(((size_t)b * C_N + c) * O_N + (r0 + rr)) * O_N + q] = o;
            }
        }
    }
}

extern "C" void kernel_launch(void* const* d_in, const int* in_sizes, int n_in,
                              void* d_out, int out_size, void* d_ws, size_t ws_size,
                              hipStream_t stream) {
    const float* images = (const float*)d_in[0];
    const float* locs   = (const float*)d_in[1];
    float* out = (float*)d_out;

    racnn_crop_resize<<<(O_N / RPB) * B_N, BLOCK, 0, stream>>>(images, locs, out);
}

// Round 6
// 32.344 us; speedup vs baseline: 1.3131x; 1.0087x over previous
//
#include <hip/hip_runtime.h>

// RACNN crop+mask+resize fused kernel — 2 rows/block, hoisted column params,
// float4 staging, XCD row-band swizzle (load-balanced across XCDs).
// images: (64, 3, 448, 448) f32, locs: (64, 3) f32 -> out: (64, 3, 224, 224) f32
//
// One block per (b, 2 output rows), all 3 channels, BLOCK=256 (8 blocks/CU).
// Row-axis (axis 2) interp params are block-uniform; source rows pre-combined
// into LDS via float4 loads over the 4-aligned column window:
//   comb[rr][c][j] = img[i0r][j]*mr0*(1-frr) + img[i1r][j]*mr1*frr
// Column (axis 3) params are computed BEFORE the staging loop so the expf/VALU
// work overlaps the global-load latency. Output pixel = 2 LDS reads + lerp.
// Identical to the reference modulo FP reassociation (absmax 0.016 << 0.092).
//
// XCD swizzle: per-batch crop read volume varies 2.26x (tl in [149.3,298.7]).
// Chunking whole batches per XCD (round 4/5) leaves ~11% per-XCD work spread.
// Instead XCD x owns output-row band [x*28, x*28+28) of EVERY batch: work is
// exactly 1/8 of total per XCD, and adjacent-row source overlap stays in-band
// (same XCD L2). Consecutive same-XCD hw blocks = (same b, adjacent r0).

#define B_N 64
#define C_N 3
#define S_N 448
#define O_N 224
#define BLOCK 256
#define RPB 2
#define NXCD 8
#define NV_PAD 113  // max float4 per channel window (112) + 1 pad

__device__ __forceinline__ float sigm(float x) {
    return 1.0f / (1.0f + __expf(-x));
}

__global__ __launch_bounds__(BLOCK) void racnn_crop_resize(
    const float* __restrict__ images,
    const float* __restrict__ locs,
    float* __restrict__ out) {
    __shared__ float4 comb4[RPB][C_N][NV_PAD];  // 10848 B

    // --- XCD row-band swizzle (bijective over 7168 blocks) ---
    const int bid = blockIdx.x;
    const int x = bid % NXCD;                    // XCD id (round-robin dispatch)
    const int m = bid / NXCD;                    // within-XCD index [0, 896)
    const int BPB = O_N / RPB / NXCD;            // 14 blocks per (xcd, batch)
    const int b = m / BPB;                       // [0, 64)
    const int lb = m - b * BPB;                  // [0, 14)
    const int r0 = x * (O_N / NXCD) + lb * RPB;  // row band per XCD
    const int tid = threadIdx.x;

    const float fS = (float)S_N;

    // --- per-batch box params (match reference clip/floor/where order) ---
    float tx = locs[b * 3 + 0];
    float ty = locs[b * 3 + 1];
    float tl = locs[b * 3 + 2];
    tl = fminf(fmaxf(tl, fS / 3.0f), fS * (2.0f / 3.0f));
    tx = fminf(fmaxf(tx, tl), fS - tl);
    ty = fminf(fmaxf(ty, tl), fS - tl);

    float w_off = fmaxf(floorf(tx - tl), 0.0f);
    float w_end = (tx + tl < fS) ? floorf(tx + tl) : fS;
    float h_off = fmaxf(floorf(ty - tl), 0.0f);
    float h_end = (ty + tl < fS) ? floorf(ty + tl) : fS;

    const float inv_o1 = 1.0f / (float)(O_N - 1);

    // --- 4-aligned gathered column window (h_off/h_end are integral) ---
    const int col_lo = (int)h_off;
    const int col_hi = min((int)h_end, S_N - 1);
    const int c4lo = col_lo >> 2;
    const int nv = (col_hi >> 2) - c4lo + 1;  // <= 112 float4 per channel

    // --- column (axis-3) params: computed NOW so expf overlaps load latency ---
    int x0 = 0, x1 = 0;
    float wa = 0.0f, wb = 0.0f;
    {
        const int q = tid;  // valid for tid < O_N; harmless garbage otherwise
        float src_q = h_off + (float)q * (h_end - h_off - 1.0f) * inv_o1;
        float f0q = fminf(fmaxf(floorf(src_q), 0.0f), fS - 1.0f);
        int i0q = (int)f0q;
        int i1q = min(i0q + 1, S_N - 1);
        float frq = src_q - f0q;
        float mq0 = sigm(10.0f * (f0q - h_off)) - sigm(10.0f * (f0q - h_end));
        float mq1 = sigm(10.0f * ((float)i1q - h_off)) - sigm(10.0f * ((float)i1q - h_end));
        const int wlim = nv * 4 - 1;
        const int base_col = c4lo << 2;
        x0 = min(max(i0q - base_col, 0), wlim);
        x1 = min(max(i1q - base_col, 0), wlim);
        wa = mq0 * (1.0f - frq);
        wb = mq1 * frq;
    }

    // --- row (axis-2) interp params per local row (block-uniform) ---
    size_t off0_[RPB], off1_[RPB];
    float Ar[RPB], Br[RPB];
    const size_t plane4 = (size_t)(S_N * S_N / 4);
    const size_t row4 = S_N / 4;  // 112
#pragma unroll
    for (int rr = 0; rr < RPB; ++rr) {
        float src_r = w_off + (float)(r0 + rr) * (w_end - w_off - 1.0f) * inv_o1;
        float f0r = fminf(fmaxf(floorf(src_r), 0.0f), fS - 1.0f);
        int i0r = (int)f0r;
        int i1r = min(i0r + 1, S_N - 1);
        float frr = src_r - f0r;
        float mr0 = sigm(10.0f * (f0r - w_off)) - sigm(10.0f * (f0r - w_end));
        float mr1 = sigm(10.0f * ((float)i1r - w_off)) - sigm(10.0f * ((float)i1r - w_end));
        Ar[rr] = mr0 * (1.0f - frr);
        Br[rr] = mr1 * frr;
        off0_[rr] = (size_t)i0r * row4 + c4lo;
        off1_[rr] = (size_t)i1r * row4 + c4lo;
    }

    // --- stage combined rows into LDS (coalesced float4) ---
    const float4* img4 = reinterpret_cast<const float4*>(images);
    const size_t base4 = (size_t)b * C_N * plane4;

    const int total = RPB * C_N * nv;  // <= 672 -> at most 3 iterations
    for (int v = tid; v < total; v += BLOCK) {
        int cc = v / nv;          // 0..5
        int j4 = v - cc * nv;
        int rr = cc >= C_N;       // RPB=2
        int c = cc - rr * C_N;
        const size_t cbase = base4 + (size_t)c * plane4;
        const float4 a = img4[cbase + off0_[rr] + j4];
        const float4 bb = img4[cbase + off1_[rr] + j4];
        float4 o;
        o.x = a.x * Ar[rr] + bb.x * Br[rr];
        o.y = a.y * Ar[rr] + bb.y * Br[rr];
        o.z = a.z * Ar[rr] + bb.z * Br[rr];
        o.w = a.w * Ar[rr] + bb.w * Br[rr];
        comb4[rr][c][j4] = o;
    }
    __syncthreads();

    // --- column lerp + store: one q per thread, 2 rows x 3 channels ---
    if (tid < O_N) {
        const int q = tid;
        const float* combf = reinterpret_cast<const float*>(comb4);
#pragma unroll
        for (int rr = 0; rr < RPB; ++rr) {
#pragma unroll
            for (int c = 0; c < C_N; ++c) {
                const float* row = combf + ((size_t)rr * C_N + c) * (NV_PAD * 4);
                float o = row[x0] * wa + row[x1] * wb;
                out[(((size_t)b * C_N + c) * O_N + (r0 + rr)) * O_N + q] = o;
            }
        }
    }
}

extern "C" void kernel_launch(void* const* d_in, const int* in_sizes, int n_in,
                              void* d_out, int out_size, void* d_ws, size_t ws_size,
                              hipStream_t stream) {
    const float* images = (const float*)d_in[0];
    const float* locs   = (const float*)d_in[1];
    float* out = (float*)d_out;

    racnn_crop_resize<<<(O_N / RPB) * B_N, BLOCK, 0, stream>>>(images, locs, out);
}